// Round 11
// baseline (325.632 us; speedup 1.0000x reference)
//
#include <hip/hip_runtime.h>
#include <hip/hip_bf16.h>
#include <stdint.h>

#define NB 32
#define NS 2048
#define ND 1024
#define NA 1024
#define MASK_NEG 1e30f

#define BM 256
#define BN 256
#define BK 64
#define TT_TOTAL 64  // 4 a-tiles x 16 K-tiles

typedef __attribute__((ext_vector_type(4))) float f32x4;
typedef __attribute__((ext_vector_type(8))) __bf16 bf16x8;

__device__ __forceinline__ void glds16(const void* g, void* l) {
  __builtin_amdgcn_global_load_lds(
      (const __attribute__((address_space(1))) uint32_t*)g,
      (__attribute__((address_space(3))) uint32_t*)(uintptr_t)l, 16, 0, 0);
}

// ---------------- fp32 -> bf16 bulk convert ----------------
__global__ __launch_bounds__(256) void cvt_bf16(const float* __restrict__ in,
                                                __bf16* __restrict__ out, int n8) {
  long i = blockIdx.x * 256 + threadIdx.x;
  const long stride = (long)gridDim.x * 256;
  for (; i < n8; i += stride) {
    f32x4 a = ((const f32x4*)in)[2 * i];
    f32x4 b = ((const f32x4*)in)[2 * i + 1];
    bf16x8 o;
#pragma unroll
    for (int j = 0; j < 4; ++j) { o[j] = (__bf16)a[j]; o[4 + j] = (__bf16)b[j]; }
    ((bf16x8*)out)[i] = o;
  }
}

// ---------------- w1q[b,a] = query[b,:] . W1[a,:]  (fp32) ----------------
__global__ __launch_bounds__(256) void w1q_kernel(const float* __restrict__ q,
                                                  const float* __restrict__ W1,
                                                  float* __restrict__ w1q) {
  const int b = blockIdx.x;
  const int a0 = blockIdx.y * 64;
  const int t = threadIdx.x;
  const int al = t >> 2;
  const int part = t & 3;
  const float* wrow = W1 + (size_t)(a0 + al) * ND + part * 256;
  const float* qrow = q + (size_t)b * ND + part * 256;
  float sum = 0.f;
#pragma unroll 8
  for (int i = 0; i < 256; i += 4) {
    float4 w = *reinterpret_cast<const float4*>(wrow + i);
    float4 x = *reinterpret_cast<const float4*>(qrow + i);
    sum += w.x * x.x + w.y * x.y + w.z * x.z + w.w * x.w;
  }
  __shared__ float red[256];
  red[t] = sum;
  __syncthreads();
  if (t < 64) {
    w1q[(size_t)b * NA + a0 + t] = red[t * 4] + red[t * 4 + 1] + red[t * 4 + 2] + red[t * 4 + 3];
  }
}

// ---------------- fused scores GEMM: 8-slot A-ring + reg-B, counted vmcnt ----------------
// R5 structure (correctness-verified) with the clobber bug fixed: all waitcnt
// asms are BARE (no "memory" clobber -- a clobber makes the compiler insert a
// hidden vmcnt(0) before the asm because global_load_lds writes LDS), each
// followed by sched_barrier(0) (rule 18).
// A (keys) LDS: ring of 8 half-tile slots (128 rows x 64 k bf16 = 16 KB each);
// half (tau,h) -> slot (2tau+h)&7, staged during window tau-2, read during tau.
// B (W2): straight to registers from L2 one K-tile ahead; compiler-counted
// vmcnt covers them (B-loads issue BEFORE stagings each window -> FIFO-safe).
// Window-end vmcnt(12) leaves B(tau+1)[8] + A(tau+2)[4] in flight; never
// drains to 0 in the main loop. LDS traffic halves vs R8 (B has no ds_reads).
__global__ __launch_bounds__(512, 1) void score_gemm8(
    const __bf16* __restrict__ keysb, const __bf16* __restrict__ W2b,
    const float* __restrict__ w1q, const float* __restrict__ vvec,
    float* __restrict__ scores) {
  __shared__ __bf16 ldsA[8 * 8192];   // 128 KB ring
  __shared__ float sm_w1q[NA];        // 4 KB
  __shared__ float sm_v[NA];          // 4 KB
  __shared__ float sm_part[4][BM];    // 4 KB

  const int t = threadIdx.x;
  const int bs0 = blockIdx.x * BM;
  const int b = bs0 >> 11;
  const int lane = t & 63;
  const int wid = t >> 6;
  const int wr = wid >> 2;   // 0..1: 128-row half of output tile
  const int wc = wid & 3;    // 0..3: 64-col quarter
  const int lrow = lane & 15;
  const int ko = lane >> 4;

  for (int i = t; i < NA; i += 512) {
    sm_w1q[i] = w1q[(size_t)b * NA + i];
    sm_v[i] = vvec[i];
  }
  for (int i = t; i < 4 * BM; i += 512) ((float*)sm_part)[i] = 0.f;
  __syncthreads();

  // staging lane geometry (R2-verified involution): chunk = 1KB = 8 rows;
  // this thread loads chunk wid and wid+8 of each 16 KB half-tile.
  const int srow = lane >> 3;
  const int scol = (lane & 7) ^ srow;
  const size_t aoff0 = (size_t)(bs0 + wid * 8 + srow) * ND + scol * 8;
  const size_t aoff1 = (size_t)(bs0 + (wid + 8) * 8 + srow) * ND + scol * 8;
  const int c0_ = wid * 1024;
  const int c1_ = (wid + 8) * 1024;

  // fragment read slots (pre-swizzled)
  const int sl0 = ko ^ (lrow & 7);
  const int sl1 = (4 + ko) ^ (lrow & 7);

  f32x4 acc[8][4];
#pragma unroll
  for (int mi = 0; mi < 8; ++mi)
#pragma unroll
    for (int ni = 0; ni < 4; ++ni) acc[mi][ni] = f32x4{0.f, 0.f, 0.f, 0.f};

  bf16x8 af[4][2];
  bf16x8 bE[4][2], bO[4][2];

#define STAGE_A(TT, H)                                                          \
  do {                                                                          \
    if ((TT) < TT_TOTAL) {                                                      \
      const int slot_ = (2 * (TT) + (H)) & 7;                                   \
      const size_t go_ = (size_t)(H) * 128 * ND + (size_t)(((TT) & 15) * BK);   \
      glds16(keysb + aoff0 + go_, (char*)ldsA + (slot_ << 14) + c0_);           \
      glds16(keysb + aoff1 + go_, (char*)ldsA + (slot_ << 14) + c1_);           \
    }                                                                           \
  } while (0)

#define LOAD_BFRAGS(DST, TT)                                                    \
  do {                                                                          \
    const int a0_ = ((TT) >> 4) * BN;                                           \
    const int k0_ = ((TT) & 15) * BK;                                           \
    _Pragma("unroll") for (int ni = 0; ni < 4; ++ni)                            \
        _Pragma("unroll") for (int kk = 0; kk < 2; ++kk)                        \
            DST[ni][kk] = *reinterpret_cast<const bf16x8*>(                     \
                W2b + (size_t)(a0_ + wc * 64 + ni * 16 + lrow) * ND + k0_ +     \
                kk * 32 + ko * 8);                                              \
  } while (0)

#define READ_AF(TAU, MIH)                                                       \
  do {                                                                          \
    const char* base_ = (const char*)ldsA + (((2 * (TAU) + wr) & 7) << 14);     \
    _Pragma("unroll") for (int mi = 0; mi < 4; ++mi) {                          \
      const int rb_ = (((MIH)*4 + mi) * 16 + lrow) * 128;                       \
      af[mi][0] = *reinterpret_cast<const bf16x8*>(base_ + rb_ + sl0 * 16);     \
      af[mi][1] = *reinterpret_cast<const bf16x8*>(base_ + rb_ + sl1 * 16);     \
    }                                                                           \
  } while (0)

#define MFMAQ(MIH, NIH, CUR)                                                    \
  _Pragma("unroll") for (int mi = 0; mi < 4; ++mi)                              \
      _Pragma("unroll") for (int nq = 0; nq < 2; ++nq) {                        \
    acc[(MIH)*4 + mi][(NIH)*2 + nq] = __builtin_amdgcn_mfma_f32_16x16x32_bf16(  \
        af[mi][0], CUR[(NIH)*2 + nq][0], acc[(MIH)*4 + mi][(NIH)*2 + nq], 0, 0, 0); \
    acc[(MIH)*4 + mi][(NIH)*2 + nq] = __builtin_amdgcn_mfma_f32_16x16x32_bf16(  \
        af[mi][1], CUR[(NIH)*2 + nq][1], acc[(MIH)*4 + mi][(NIH)*2 + nq], 0, 0, 0); \
  }

#define SETP1 __builtin_amdgcn_s_setprio(1)
#define SETP0 __builtin_amdgcn_s_setprio(0)
#define BAR __builtin_amdgcn_s_barrier()
#define SB __builtin_amdgcn_sched_barrier(0)

#define WINDOW(TAU, CUR, NXT)                                                   \
  do {                                                                          \
    /* wph1: B-frags for next tile FIRST (FIFO), stage A(tau+2,h0), af-lo */    \
    if ((TAU) + 1 < TT_TOTAL) LOAD_BFRAGS(NXT, (TAU) + 1);                      \
    STAGE_A((TAU) + 2, 0);                                                      \
    READ_AF(TAU, 0);                                                            \
    SETP1; MFMAQ(0, 0, CUR); SETP0; BAR;                                        \
    /* wph2: Q(lo,hi) */                                                        \
    SETP1; MFMAQ(0, 1, CUR); SETP0; BAR;                                        \
    /* wph3: stage A(tau+2,h1), af-hi, Q(hi,lo) */                              \
    STAGE_A((TAU) + 2, 1);                                                      \
    READ_AF(TAU, 1);                                                            \
    SETP1; MFMAQ(1, 0, CUR); SETP0; BAR;                                        \
    /* wph4: Q(hi,hi), counted-vmcnt checkpoint (BARE asm + SB) */              \
    SETP1; MFMAQ(1, 1, CUR); SETP0;                                             \
    if ((TAU) < TT_TOTAL - 2) {                                                 \
      asm volatile("s_waitcnt vmcnt(12)");                                      \
    } else {                                                                    \
      asm volatile("s_waitcnt vmcnt(8)");                                       \
    }                                                                           \
    SB;                                                                         \
    BAR;                                                                        \
  } while (0)

#define EPILOGUE(ATILE)                                                         \
  do {                                                                          \
    const int a0e_ = (ATILE)*BN;                                                \
    float w1v[4], vv[4];                                                        \
    _Pragma("unroll") for (int ni = 0; ni < 4; ++ni) {                          \
      const int a_ = a0e_ + wc * 64 + ni * 16 + lrow;                           \
      w1v[ni] = sm_w1q[a_];                                                     \
      vv[ni] = sm_v[a_];                                                        \
    }                                                                           \
    _Pragma("unroll") for (int mi = 0; mi < 8; ++mi)                            \
        _Pragma("unroll") for (int r = 0; r < 4; ++r) {                         \
      float p = 0.f;                                                            \
      _Pragma("unroll") for (int ni = 0; ni < 4; ++ni) {                        \
        const float x = acc[mi][ni][r] + w1v[ni];                               \
        const float e = __expf(2.f * x);                                        \
        p += (1.f - 2.f * __builtin_amdgcn_rcpf(e + 1.f)) * vv[ni];             \
      }                                                                         \
      p += __shfl_xor(p, 1);                                                    \
      p += __shfl_xor(p, 2);                                                    \
      p += __shfl_xor(p, 4);                                                    \
      p += __shfl_xor(p, 8);                                                    \
      if (lrow == 0) sm_part[wc][wr * 128 + mi * 16 + ko * 4 + r] += p;         \
    }                                                                           \
    _Pragma("unroll") for (int mi = 0; mi < 8; ++mi)                            \
        _Pragma("unroll") for (int ni = 0; ni < 4; ++ni)                        \
            acc[mi][ni] = f32x4{0.f, 0.f, 0.f, 0.f};                            \
  } while (0)

  // ---- prologue: A(0),A(1) staged; B(0) into bE; wait A(0) only ----
  STAGE_A(0, 0);
  STAGE_A(0, 1);
  STAGE_A(1, 0);
  STAGE_A(1, 1);
  LOAD_BFRAGS(bE, 0);
  asm volatile("s_waitcnt vmcnt(12)");
  SB;
  BAR;

  for (int tau = 0; tau < TT_TOTAL; tau += 2) {
    WINDOW(tau, bE, bO);
    WINDOW(tau + 1, bO, bE);
    if (((tau + 1) & 15) == 15) EPILOGUE((tau + 1) >> 4);
  }

  __syncthreads();
  if (t < BM)
    scores[bs0 + t] = sm_part[0][t] + sm_part[1][t] + sm_part[2][t] + sm_part[3][t];

#undef STAGE_A
#undef LOAD_BFRAGS
#undef READ_AF
#undef MFMAQ
#undef WINDOW
#undef EPILOGUE
#undef SETP1
#undef SETP0
#undef BAR
#undef SB
}

// ---------------- masked softmax ----------------
__global__ __launch_bounds__(256) void softmax_kernel(const float* __restrict__ scores,
                                                      const int* __restrict__ mask,
                                                      float* __restrict__ out) {
  const int b = blockIdx.x;
  const int t = threadIdx.x;
  float sc[8];
  float mx = -3.4e38f;
#pragma unroll
  for (int j = 0; j < 8; ++j) {
    int i = t + j * 256;
    float s = scores[b * NS + i];
    if (mask[b * NS + i] == 0) s -= MASK_NEG;
    sc[j] = s;
    mx = fmaxf(mx, s);
  }
#pragma unroll
  for (int off = 1; off < 64; off <<= 1) mx = fmaxf(mx, __shfl_xor(mx, off));
  __shared__ float redm[4];
  __shared__ float reds[4];
  if ((t & 63) == 0) redm[t >> 6] = mx;
  __syncthreads();
  mx = fmaxf(fmaxf(redm[0], redm[1]), fmaxf(redm[2], redm[3]));
  float e[8];
  float sum = 0.f;
#pragma unroll
  for (int j = 0; j < 8; ++j) {
    e[j] = __expf(sc[j] - mx);
    sum += e[j];
  }
#pragma unroll
  for (int off = 1; off < 64; off <<= 1) sum += __shfl_xor(sum, off);
  if ((t & 63) == 0) reds[t >> 6] = sum;
  __syncthreads();
  sum = reds[0] + reds[1] + reds[2] + reds[3];
  float inv = 1.f / sum;
#pragma unroll
  for (int j = 0; j < 8; ++j) out[b * NS + t + j * 256] = e[j] * inv;
}

extern "C" void kernel_launch(void* const* d_in, const int* in_sizes, int n_in,
                              void* d_out, int out_size, void* d_ws, size_t ws_size,
                              hipStream_t stream) {
  const float* q = (const float*)d_in[0];
  const float* keysf = (const float*)d_in[1];
  const int* mask = (const int*)d_in[2];
  const float* W1 = (const float*)d_in[3];
  const float* W2f = (const float*)d_in[4];
  const float* v = (const float*)d_in[5];
  float* out = (float*)d_out;

  float* scores = (float*)d_ws;                                 // 256 KB
  float* w1q = scores + NB * NS;                                // 128 KB
  __bf16* W2b = (__bf16*)(w1q + NB * NA);                       // 2 MB
  __bf16* keysb = (__bf16*)((char*)W2b + (size_t)NA * ND * 2);  // 128 MB

  cvt_bf16<<<512, 256, 0, stream>>>(W2f, W2b, NA * ND / 8);
  cvt_bf16<<<2048, 256, 0, stream>>>(keysf, keysb, (int)((size_t)NB * NS * ND / 8));
  w1q_kernel<<<dim3(NB, NA / 64), 256, 0, stream>>>(q, W1, w1q);
  score_gemm8<<<NB * NS / BM, 512, 0, stream>>>(keysb, W2b, w1q, v, scores);
  softmax_kernel<<<NB, 256, 0, stream>>>(scores, mask, out);
}

// Round 12
// 236.349 us; speedup vs baseline: 1.3778x; 1.3778x over previous
//
#include <hip/hip_runtime.h>
#include <hip/hip_bf16.h>
#include <stdint.h>

#define NB 32
#define NS 2048
#define ND 1024
#define NA 1024
#define MASK_NEG 1e30f

#define BM 256
#define BN 256
#define BK 64
#define NTILES 64  // 4 a-tiles x 16 K-tiles

typedef __attribute__((ext_vector_type(4))) float f32x4;
typedef __attribute__((ext_vector_type(8))) __bf16 bf16x8;

__device__ __forceinline__ void glds16(const void* g, void* l) {
  __builtin_amdgcn_global_load_lds(
      (const __attribute__((address_space(1))) uint32_t*)g,
      (__attribute__((address_space(3))) uint32_t*)(uintptr_t)l, 16, 0, 0);
}

// ---------------- zero scores (atomic accumulation target) ----------------
__global__ void zero_f32(float* __restrict__ p, int n) {
  int i = blockIdx.x * 256 + threadIdx.x;
  if (i < n) p[i] = 0.f;
}

// ---------------- fp32 -> bf16 bulk convert (W2 only, 2 MB) ----------------
__global__ __launch_bounds__(256) void cvt_bf16(const float* __restrict__ in,
                                                __bf16* __restrict__ out, int n8) {
  long i = blockIdx.x * 256 + threadIdx.x;
  const long stride = (long)gridDim.x * 256;
  for (; i < n8; i += stride) {
    f32x4 a = ((const f32x4*)in)[2 * i];
    f32x4 b = ((const f32x4*)in)[2 * i + 1];
    bf16x8 o;
#pragma unroll
    for (int j = 0; j < 4; ++j) { o[j] = (__bf16)a[j]; o[4 + j] = (__bf16)b[j]; }
    ((bf16x8*)out)[i] = o;
  }
}

// ---------------- w1q[b,a] = query[b,:] . W1[a,:]  (fp32) ----------------
__global__ __launch_bounds__(256) void w1q_kernel(const float* __restrict__ q,
                                                  const float* __restrict__ W1,
                                                  float* __restrict__ w1q) {
  const int b = blockIdx.x;
  const int a0 = blockIdx.y * 64;
  const int t = threadIdx.x;
  const int al = t >> 2;
  const int part = t & 3;
  const float* wrow = W1 + (size_t)(a0 + al) * ND + part * 256;
  const float* qrow = q + (size_t)b * ND + part * 256;
  float sum = 0.f;
#pragma unroll 8
  for (int i = 0; i < 256; i += 4) {
    float4 w = *reinterpret_cast<const float4*>(wrow + i);
    float4 x = *reinterpret_cast<const float4*>(qrow + i);
    sum += w.x * x.x + w.y * x.y + w.z * x.z + w.w * x.w;
  }
  __shared__ float red[256];
  red[t] = sum;
  __syncthreads();
  if (t < 64) {
    w1q[(size_t)b * NA + a0 + t] = red[t * 4] + red[t * 4 + 1] + red[t * 4 + 2] + red[t * 4 + 3];
  }
}

// ---------------- fused scores GEMM: fp32-direct A staging (no cvt kernel) ----------------
// A (keys, fp32): ring of 6 quarter-tiles (64 rows x 64 k x 4B = 16 KB) in LDS,
// slot (4*tile+q) % 6; staged one tile ahead: q0@ph1, q2@ph2, q1@ph3, q3@ph4
// (evens read at ph1 of the next tile, odds at ph3 -- deadlines audited).
// Converted fp32->bf16 in-register during the LDS->fragment read.
// B (W2, bf16): ring of 4 half-tiles (128 rows x 64 k = 16 KB), h0@ph1 h1@ph2.
// Counted waits: vmcnt(8) at ph2-end (forces prev tile's ph3/ph4 stages),
// vmcnt(4) at ph4-end (forces this tile's ph1/ph2); >=2-phase flight for all.
// Tail tau=63: vmcnt(0) at ph2-end. LDS = 96+64 = 160 KB exactly; w1q/v read
// from global at the per-a-tile epilogue; scores accumulated via atomicAdd.
// Swizzles (conflict-free, R2-lineage): A store col16 = (t&15)^((t>>4)&15),
// read slot = (kk*8+ko*2(+1))^lrow; B as R8.
__global__ __launch_bounds__(512, 1) void score_gemm(
    const float* __restrict__ keysf, const __bf16* __restrict__ W2b,
    const float* __restrict__ w1q, const float* __restrict__ vvec,
    float* __restrict__ scores) {
  __shared__ __attribute__((aligned(1024))) char ldsA[6 * 16384];  // 96 KB fp32 quarters
  __shared__ __attribute__((aligned(1024))) char ldsB[4 * 16384];  // 64 KB bf16 halves

  const int t = threadIdx.x;
  const int bs0 = blockIdx.x * BM;
  const int b = bs0 >> 11;  // / NS
  const int lane = t & 63;
  const int wid = t >> 6;
  const int wr = wid >> 2;   // 0..1: 128-row half of output
  const int wc = wid & 3;    // 0..3: 64-col quarter of output
  const int lrow = lane & 15;
  const int ko = lane >> 4;

  // staging maps (thread-linear LDS dest, inverse-swizzled global source)
  const int rowA = t >> 4;                      // 0..31 (A: 16 slots/256B row)
  const int scolA = (t & 15) ^ (rowA & 15);     // col16 unit (4 floats)
  const int rowB = t >> 3;                      // 0..63 (B: 8 slots/128B row)
  const int scolB = (t & 7) ^ (rowB & 7);       // col16 unit (8 bf16)

  // fragment read slots (pre-swizzled)
  const int uA0 = ko * 2, uA1 = 8 + ko * 2;     // fp32 16B-units for kk=0/1
  const int sA00 = uA0 ^ lrow, sA01 = (uA0 + 1) ^ lrow;
  const int sA10 = uA1 ^ lrow, sA11 = (uA1 + 1) ^ lrow;
  const int sB0 = ko ^ (lrow & 7), sB1 = (4 + ko) ^ (lrow & 7);

  f32x4 acc[8][4];
#pragma unroll
  for (int mi = 0; mi < 8; ++mi)
#pragma unroll
    for (int ni = 0; ni < 4; ++ni) acc[mi][ni] = f32x4{0.f, 0.f, 0.f, 0.f};

  bf16x8 af[4][2], bfr[2][2];

#define STAGE_A(T, Q)                                                           \
  do {                                                                          \
    if ((T) < NTILES) {                                                         \
      const unsigned slot_ = (4u * (unsigned)(T) + (unsigned)(Q)) % 6u;         \
      char* d_ = ldsA + slot_ * 16384 + t * 16;                                 \
      const size_t r0_ = (size_t)(bs0 + (Q)*64 + rowA);                         \
      const int kf_ = ((T)&15) * 64 + scolA * 4;                                \
      glds16(keysf + r0_ * ND + kf_, d_);                                       \
      glds16(keysf + (r0_ + 32) * ND + kf_, d_ + 8192);                         \
    }                                                                           \
  } while (0)

#define STAGE_B(T, H)                                                           \
  do {                                                                          \
    if ((T) < NTILES) {                                                         \
      const unsigned slot_ = (2u * (unsigned)(T) + (unsigned)(H)) % 4u;         \
      char* d_ = ldsB + slot_ * 16384 + t * 16;                                 \
      const size_t r0_ = (size_t)(((T) >> 4) * 256 + (H)*128 + rowB);           \
      const int ke_ = (((T)&15) * 64) + scolB * 8;                              \
      glds16(W2b + r0_ * ND + ke_, d_);                                         \
      glds16(W2b + (r0_ + 64) * ND + ke_, d_ + 8192);                           \
    }                                                                           \
  } while (0)

#define SB_ __builtin_amdgcn_sched_barrier(0)
#define P1 __builtin_amdgcn_s_setprio(1)
#define P0 __builtin_amdgcn_s_setprio(0)
#define BAR __builtin_amdgcn_s_barrier()

  // PHASE: stage -> reads (af fresh on N_==0, fp32->bf16 cvt; bfr fresh) ->
  // BAR -> lgkm(0) -> 16 MFMA -> counted vmcnt (WM) -> BAR.  (R8 discipline)
#define PHASE(M_, N_, STAGES, WM)                                               \
  do {                                                                          \
    STAGES;                                                                     \
    if ((N_) == 0) {                                                            \
      const char* Ab_ = ldsA + ((4u * (unsigned)tau + 2u * wr + (M_)) % 6u) * 16384; \
      _Pragma("unroll") for (int mi = 0; mi < 4; ++mi) {                        \
        const int rb_ = (mi * 16 + lrow) * 256;                                 \
        f32x4 l0 = *reinterpret_cast<const f32x4*>(Ab_ + rb_ + sA00 * 16);      \
        f32x4 l1 = *reinterpret_cast<const f32x4*>(Ab_ + rb_ + sA01 * 16);      \
        f32x4 h0 = *reinterpret_cast<const f32x4*>(Ab_ + rb_ + sA10 * 16);      \
        f32x4 h1 = *reinterpret_cast<const f32x4*>(Ab_ + rb_ + sA11 * 16);      \
        _Pragma("unroll") for (int j = 0; j < 4; ++j) {                         \
          af[mi][0][j] = (__bf16)l0[j]; af[mi][0][4 + j] = (__bf16)l1[j];       \
          af[mi][1][j] = (__bf16)h0[j]; af[mi][1][4 + j] = (__bf16)h1[j];       \
        }                                                                       \
      }                                                                         \
    }                                                                           \
    {                                                                           \
      const char* Bb_ = ldsB + ((2u * (unsigned)tau + (wc >> 1)) % 4u) * 16384; \
      _Pragma("unroll") for (int nq = 0; nq < 2; ++nq) {                        \
        const int rb_ = (((wc & 1) * 4 + (N_)*2 + nq) * 16 + lrow) * 128;       \
        bfr[nq][0] = *reinterpret_cast<const bf16x8*>(Bb_ + rb_ + sB0 * 16);    \
        bfr[nq][1] = *reinterpret_cast<const bf16x8*>(Bb_ + rb_ + sB1 * 16);    \
      }                                                                         \
    }                                                                           \
    BAR;                                                                        \
    asm volatile("s_waitcnt lgkmcnt(0)");                                       \
    SB_;                                                                        \
    P1;                                                                         \
    _Pragma("unroll") for (int mi = 0; mi < 4; ++mi)                            \
        _Pragma("unroll") for (int nq = 0; nq < 2; ++nq) {                      \
      acc[(M_)*4 + mi][(N_)*2 + nq] = __builtin_amdgcn_mfma_f32_16x16x32_bf16(  \
          af[mi][0], bfr[nq][0], acc[(M_)*4 + mi][(N_)*2 + nq], 0, 0, 0);       \
      acc[(M_)*4 + mi][(N_)*2 + nq] = __builtin_amdgcn_mfma_f32_16x16x32_bf16(  \
          af[mi][1], bfr[nq][1], acc[(M_)*4 + mi][(N_)*2 + nq], 0, 0, 0);       \
    }                                                                           \
    P0;                                                                         \
    if ((WM) == 1) {                                                            \
      if (tau < NTILES - 1) { asm volatile("s_waitcnt vmcnt(8)"); }             \
      else { asm volatile("s_waitcnt vmcnt(0)"); }                              \
      SB_;                                                                      \
    } else if ((WM) == 2) {                                                     \
      if (tau < NTILES - 1) { asm volatile("s_waitcnt vmcnt(4)"); SB_; }        \
    }                                                                           \
    BAR;                                                                        \
  } while (0)

  // ---- prologue: full tile 0 (A quarters 0-3, B halves 0-1); drain once ----
  STAGE_A(0, 0);
  STAGE_A(0, 1);
  STAGE_A(0, 2);
  STAGE_A(0, 3);
  STAGE_B(0, 0);
  STAGE_B(0, 1);
  __syncthreads();  // drains vmcnt before first reads

  for (int tau = 0; tau < NTILES; ++tau) {
    PHASE(0, 0, { STAGE_A(tau + 1, 0); STAGE_B(tau + 1, 0); }, 0);  // ph1
    PHASE(0, 1, { STAGE_A(tau + 1, 2); STAGE_B(tau + 1, 1); }, 1);  // ph2 + vm(8)
    PHASE(1, 0, { STAGE_A(tau + 1, 1); }, 0);                       // ph3
    PHASE(1, 1, { STAGE_A(tau + 1, 3); }, 2);                       // ph4 + vm(4)

    // ---- per-a-tile epilogue: tanh + v-weight -> atomic scores ----
    if ((tau & 15) == 15) {
      const int a0 = (tau >> 4) * BN;
      float w1v[4], vv[4];
#pragma unroll
      for (int ni = 0; ni < 4; ++ni) {
        const int a = a0 + wc * 64 + ni * 16 + lrow;
        w1v[ni] = w1q[(size_t)b * NA + a];
        vv[ni] = vvec[a];
      }
#pragma unroll
      for (int mi = 0; mi < 8; ++mi)
#pragma unroll
        for (int r = 0; r < 4; ++r) {
          float p = 0.f;
#pragma unroll
          for (int ni = 0; ni < 4; ++ni) {
            const float x = acc[mi][ni][r] + w1v[ni];
            const float e = __expf(2.f * x);
            p += (1.f - 2.f * __builtin_amdgcn_rcpf(e + 1.f)) * vv[ni];
          }
          p += __shfl_xor(p, 1);
          p += __shfl_xor(p, 2);
          p += __shfl_xor(p, 4);
          p += __shfl_xor(p, 8);
          if (lrow == 0)
            atomicAdd(&scores[bs0 + wr * 128 + mi * 16 + ko * 4 + r], p);
        }
#pragma unroll
      for (int mi = 0; mi < 8; ++mi)
#pragma unroll
        for (int ni = 0; ni < 4; ++ni) acc[mi][ni] = f32x4{0.f, 0.f, 0.f, 0.f};
    }
  }

#undef STAGE_A
#undef STAGE_B
#undef PHASE
#undef SB_
#undef P1
#undef P0
#undef BAR
}

// ---------------- masked softmax ----------------
__global__ __launch_bounds__(256) void softmax_kernel(const float* __restrict__ scores,
                                                      const int* __restrict__ mask,
                                                      float* __restrict__ out) {
  const int b = blockIdx.x;
  const int t = threadIdx.x;
  float sc[8];
  float mx = -3.4e38f;
#pragma unroll
  for (int j = 0; j < 8; ++j) {
    int i = t + j * 256;
    float s = scores[b * NS + i];
    if (mask[b * NS + i] == 0) s -= MASK_NEG;
    sc[j] = s;
    mx = fmaxf(mx, s);
  }
#pragma unroll
  for (int off = 1; off < 64; off <<= 1) mx = fmaxf(mx, __shfl_xor(mx, off));
  __shared__ float redm[4];
  __shared__ float reds[4];
  if ((t & 63) == 0) redm[t >> 6] = mx;
  __syncthreads();
  mx = fmaxf(fmaxf(redm[0], redm[1]), fmaxf(redm[2], redm[3]));
  float e[8];
  float sum = 0.f;
#pragma unroll
  for (int j = 0; j < 8; ++j) {
    e[j] = __expf(sc[j] - mx);
    sum += e[j];
  }
#pragma unroll
  for (int off = 1; off < 64; off <<= 1) sum += __shfl_xor(sum, off);
  if ((t & 63) == 0) reds[t >> 6] = sum;
  __syncthreads();
  sum = reds[0] + reds[1] + reds[2] + reds[3];
  float inv = 1.f / sum;
#pragma unroll
  for (int j = 0; j < 8; ++j) out[b * NS + t + j * 256] = e[j] * inv;
}

extern "C" void kernel_launch(void* const* d_in, const int* in_sizes, int n_in,
                              void* d_out, int out_size, void* d_ws, size_t ws_size,
                              hipStream_t stream) {
  const float* q = (const float*)d_in[0];
  const float* keysf = (const float*)d_in[1];
  const int* mask = (const int*)d_in[2];
  const float* W1 = (const float*)d_in[3];
  const float* W2f = (const float*)d_in[4];
  const float* v = (const float*)d_in[5];
  float* out = (float*)d_out;

  float* scores = (float*)d_ws;                                 // 256 KB
  float* w1q = scores + NB * NS;                                // 128 KB
  __bf16* W2b = (__bf16*)(w1q + NB * NA);                       // 2 MB

  zero_f32<<<NB * NS / 256, 256, 0, stream>>>(scores, NB * NS);
  cvt_bf16<<<512, 256, 0, stream>>>(W2f, W2b, NA * ND / 8);
  w1q_kernel<<<dim3(NB, NA / 64), 256, 0, stream>>>(q, W1, w1q);
  score_gemm<<<NB * NS / BM, 512, 0, stream>>>(keysf, W2b, w1q, v, scores);
  softmax_kernel<<<NB, 256, 0, stream>>>(scores, mask, out);
}